// Round 5
// baseline (104.687 us; speedup 1.0000x reference)
//
#include <hip/hip_runtime.h>
#include <hip/hip_bf16.h>

#define IN_DIMS  8192
#define OUT_DIMS 8192
#define NLAB     63
#define KS       8                    // split-K factor
#define KCH      (IN_DIMS / KS)       // 1024 K per workgroup
#define BK       64                   // K per tile
#define NT       (KCH / BK)           // 16 tiles
#define BN       64                   // W rows (N) per workgroup (16 per wave)
#define WAVETILE 4096                 // 16 rows x 64 f32 x 4B
#define BUFB     (4 * WAVETILE)       // per-WG bytes per buffer (4 waves)

typedef short  s16x8 __attribute__((ext_vector_type(8)));
typedef float  f32x4 __attribute__((ext_vector_type(4)));
typedef unsigned int u32;

__device__ __forceinline__ void gload16(const void* g, void* l) {
    __builtin_amdgcn_global_load_lds(
        (const __attribute__((address_space(1))) u32*)g,
        (__attribute__((address_space(3))) u32*)l, 16, 0, 0);
}

// ---- bf16 RNE pack helpers ----
__device__ __forceinline__ unsigned int rne2(float a, float b) {
    unsigned int ua = __float_as_uint(a), ub = __float_as_uint(b);
    ua += 0x7FFFu + ((ua >> 16) & 1u);
    ub += 0x7FFFu + ((ub >> 16) & 1u);
    return (ua >> 16) | (ub & 0xFFFF0000u);
}

// packed cvt: v_cvt_pk_bf16_f32 (RNE), 4 instrs per 8 floats
__device__ __forceinline__ s16x8 cvt8(float4 a, float4 b) {
    union { __hip_bfloat162 h[4]; s16x8 v; } u;
    u.h[0] = __float22bfloat162_rn(make_float2(a.x, a.y));
    u.h[1] = __float22bfloat162_rn(make_float2(a.z, a.w));
    u.h[2] = __float22bfloat162_rn(make_float2(b.x, b.y));
    u.h[3] = __float22bfloat162_rn(make_float2(b.z, b.w));
    return u.v;
}

// ---- kernel 1: Label f32 (63x8192) -> bf16 A (64x8192, row 63 zero) ----
__global__ __launch_bounds__(256) void k_prep(const float* __restrict__ L,
                                              unsigned short* __restrict__ A) {
    int e0 = (blockIdx.x * 256 + threadIdx.x) * 4;
    if (e0 >= 64 * IN_DIMS) return;
    float4 v = make_float4(0.f, 0.f, 0.f, 0.f);
    if (e0 < NLAB * IN_DIMS) v = *(const float4*)(L + e0);
    uint2 o;
    o.x = rne2(v.x, v.y);
    o.y = rne2(v.z, v.w);
    *(uint2*)(A + e0) = o;
}

// ---- kernel 2: barrier-free split-K MFMA GEMM ----
// Each wave owns 16 private W rows staged to a PRIVATE LDS region (no
// sharing -> no s_barrier anywhere). A (1MB, L1/L2-resident) is read
// directly from global. One counted s_waitcnt vmcnt(4) per tile keeps the
// next W tile's DMA in flight; waves run fully decoupled.
// LDS[row][slot16B] = global[row][slot ^ (row&7)] (pre-swizzled source),
// so compute-phase ds_read_b128 spreads evenly across banks.
__global__ __launch_bounds__(256, 4) void k_gemm(const float* __restrict__ W,
                                                 const unsigned short* __restrict__ A,
                                                 float* __restrict__ Xp) {
    __shared__ char lds[2 * BUFB];
    const int nblk = blockIdx.x & 127;   // N tile (64 W-rows)
    const int kspl = blockIdx.x >> 7;    // K split
    const int w    = threadIdx.x >> 6;   // wave 0..3
    const int l    = threadIdx.x & 63;
    const int r    = l & 15;             // frag row-in-16
    const int g    = l >> 4;             // frag k-group

    const int  n0    = nblk * BN + w * 16;   // this wave's first W row
    const long kbase = (long)kspl * KCH;

    char* wbuf0 = lds + w * WAVETILE;            // private, buffer 0
    char* wbuf1 = lds + BUFB + w * WAVETILE;     // private, buffer 1

    const int srow  = l >> 4;            // staging: row-within-4 per instr
    const int sslot = l & 15;            // staging: 16B slot

    auto stage = [&](int tt, char* buf) {
        const long k0 = kbase + (long)tt * BK;
        #pragma unroll
        for (int i = 0; i < 4; ++i) {    // 4 x 1KB: rows i*4 .. i*4+3
            int row  = i * 4 + srow;
            int slot = sslot ^ (row & 7);
            gload16(W + (long)(n0 + row) * IN_DIMS + k0 + slot * 4,
                    buf + i * 1024 + l * 16);
        }
    };

    stage(0, wbuf0);                     // prologue

    const unsigned short* ap = A + (long)r * IN_DIMS + kbase + g * 8;

    f32x4 acc0 = {0,0,0,0}, acc1 = {0,0,0,0}, acc2 = {0,0,0,0}, acc3 = {0,0,0,0};

    #pragma unroll 1
    for (int t = 0; t < NT; ++t) {
        int tn = (t + 1 < NT) ? (t + 1) : 0;        // clamped dummy on last iter
        stage(tn, ((t + 1) & 1) ? wbuf1 : wbuf0);
        asm volatile("s_waitcnt vmcnt(4)" ::: "memory");  // tile t ready, t+1 in flight
        __builtin_amdgcn_sched_barrier(0);

        const float* ldsW = (const float*)((t & 1) ? wbuf1 : wbuf0);
        const long ka = (long)t * BK;
        #pragma unroll
        for (int kk = 0; kk < 2; ++kk) {
            int s0 = ((kk * 8) + g * 2) ^ (r & 7);
            float4 w0 = *(const float4*)(ldsW + r * 64 + s0 * 4);
            float4 w1 = *(const float4*)(ldsW + r * 64 + (s0 ^ 1) * 4);
            s16x8 bw = cvt8(w0, w1);     // W[n0+r][k : kk*32+g*8 ..]
            s16x8 a0 = *(const s16x8*)(ap + ka + kk * 32);
            s16x8 a1 = *(const s16x8*)(ap + ka + kk * 32 + 16L * IN_DIMS);
            s16x8 a2 = *(const s16x8*)(ap + ka + kk * 32 + 32L * IN_DIMS);
            s16x8 a3 = *(const s16x8*)(ap + ka + kk * 32 + 48L * IN_DIMS);
            acc0 = __builtin_amdgcn_mfma_f32_16x16x32_bf16(a0, bw, acc0, 0, 0, 0);
            acc1 = __builtin_amdgcn_mfma_f32_16x16x32_bf16(a1, bw, acc1, 0, 0, 0);
            acc2 = __builtin_amdgcn_mfma_f32_16x16x32_bf16(a2, bw, acc2, 0, 0, 0);
            acc3 = __builtin_amdgcn_mfma_f32_16x16x32_bf16(a3, bw, acc3, 0, 0, 0);
        }
    }

    // D layout: lane holds D[m = tb*16 + g*4 + q][n = n0 + r]
    float* xo = Xp + (long)kspl * BN * OUT_DIMS + n0 + r;
    #pragma unroll
    for (int q = 0; q < 4; ++q) {
        int m = g * 4 + q;
        xo[(long)(m     ) * OUT_DIMS] = acc0[q];
        xo[(long)(m + 16) * OUT_DIMS] = acc1[q];
        xo[(long)(m + 32) * OUT_DIMS] = acc2[q];
        xo[(long)(m + 48) * OUT_DIMS] = acc3[q];
    }
}

// ---- kernel 3: out(63x8192) = S(63x63) @ relu(sum_k Xp + b).view(8192,63)^T ----
__global__ __launch_bounds__(256) void k_out(const float* __restrict__ Xp,
                                             const float* __restrict__ S,
                                             const float* __restrict__ b,
                                             float* __restrict__ out) {
    __shared__ float sS[NLAB * NLAB];
    __shared__ float sml[32 * NLAB];
    const int k0 = blockIdx.x * 32;

    for (int p = threadIdx.x; p < NLAB * NLAB; p += 256) sS[p] = S[p];
    for (int p = threadIdx.x; p < 32 * NLAB; p += 256) {
        int gi = k0 * NLAB + p;          // flat index into X (row-major 63x8192)
        float v = 0.f;
        #pragma unroll
        for (int s = 0; s < KS; ++s)     // reduce split-K partials
            v += Xp[(long)s * 64 * OUT_DIMS + gi];
        v += b[gi & (OUT_DIMS - 1)];
        sml[p] = v > 0.f ? v : 0.f;
    }
    __syncthreads();

    for (int p = threadIdx.x; p < NLAB * 32; p += 256) {
        int i  = p >> 5;                 // output row
        int kk = p & 31;                 // output col within tile
        const float* srow = &sS[i * NLAB];
        const float* mrow = &sml[kk * NLAB];
        float sum = 0.f;
        #pragma unroll
        for (int j = 0; j < NLAB; ++j) sum += srow[j] * mrow[j];
        out[(long)i * OUT_DIMS + k0 + kk] = sum;
    }
}

extern "C" void kernel_launch(void* const* d_in, const int* in_sizes, int n_in,
                              void* d_out, int out_size, void* d_ws, size_t ws_size,
                              hipStream_t stream) {
    const float* Label = (const float*)d_in[0];   // 63x8192
    const float* S     = (const float*)d_in[1];   // 63x63
    const float* W     = (const float*)d_in[2];   // 8192x8192
    const float* b     = (const float*)d_in[3];   // 8192
    float* out = (float*)d_out;

    unsigned short* A  = (unsigned short*)d_ws;                      // 1 MB bf16 A
    float*          Xp = (float*)((char*)d_ws + 64 * IN_DIMS * 2);   // KS x 2 MB partials

    k_prep<<<dim3((64 * IN_DIMS / 4 + 255) / 256), dim3(256), 0, stream>>>(Label, A);
    k_gemm<<<dim3(128 * KS), dim3(256), 0, stream>>>(W, A, Xp);
    k_out <<<dim3(OUT_DIMS / 32), dim3(256), 0, stream>>>(Xp, S, b, out);
}

// Round 6
// 73.661 us; speedup vs baseline: 1.4212x; 1.4212x over previous
//
#include <hip/hip_runtime.h>
#include <hip/hip_bf16.h>

#define IN_DIMS  8192
#define OUT_DIMS 8192
#define NLAB     63
#define KS       8                    // split-K factor
#define KCH      (IN_DIMS / KS)       // 1024 K per workgroup
#define BK       32                   // K per LDS tile
#define NT       (KCH / BK)           // 32 tiles
#define BN       64                   // W rows (N) per workgroup (16 per wave)

// per-buffer LDS: W 4 waves x 16 rows x 32 f32 (8KB) + A 64 rows x 32 bf16 (4KB)
#define AOFF     8192
#define BUFB     12288                // bytes per buffer
#define NBUF     3                    // triple buffer -> 2 tiles in flight

typedef short  s16x8 __attribute__((ext_vector_type(8)));
typedef float  f32x4 __attribute__((ext_vector_type(4)));
typedef unsigned int u32;

__device__ __forceinline__ void gload16(const void* g, void* l) {
    __builtin_amdgcn_global_load_lds(
        (const __attribute__((address_space(1))) u32*)g,
        (__attribute__((address_space(3))) u32*)l, 16, 0, 0);
}

// ---- bf16 RNE pack helpers ----
__device__ __forceinline__ unsigned int rne2(float a, float b) {
    unsigned int ua = __float_as_uint(a), ub = __float_as_uint(b);
    ua += 0x7FFFu + ((ua >> 16) & 1u);
    ub += 0x7FFFu + ((ub >> 16) & 1u);
    return (ua >> 16) | (ub & 0xFFFF0000u);
}

// packed cvt: v_cvt_pk_bf16_f32 (RNE), 4 instrs per 8 floats
__device__ __forceinline__ s16x8 cvt8(float4 a, float4 b) {
    union { __hip_bfloat162 h[4]; s16x8 v; } u;
    u.h[0] = __float22bfloat162_rn(make_float2(a.x, a.y));
    u.h[1] = __float22bfloat162_rn(make_float2(a.z, a.w));
    u.h[2] = __float22bfloat162_rn(make_float2(b.x, b.y));
    u.h[3] = __float22bfloat162_rn(make_float2(b.z, b.w));
    return u.v;
}

// ---- kernel 1: Label f32 (63x8192) -> bf16 A (64x8192, row 63 zero) ----
__global__ __launch_bounds__(256) void k_prep(const float* __restrict__ L,
                                              unsigned short* __restrict__ A) {
    int e0 = (blockIdx.x * 256 + threadIdx.x) * 4;
    if (e0 >= 64 * IN_DIMS) return;
    float4 v = make_float4(0.f, 0.f, 0.f, 0.f);
    if (e0 < NLAB * IN_DIMS) v = *(const float4*)(L + e0);
    uint2 o;
    o.x = rne2(v.x, v.y);
    o.y = rne2(v.z, v.w);
    *(uint2*)(A + e0) = o;
}

// ---- kernel 2: LDS-staged split-K MFMA GEMM, triple-buffer, whole grid
//      co-resident (36KB LDS -> 4 WGs/CU x 256 CUs = 1024 WGs = grid).
// Per tile per wave: 3 global_load_lds (2 W + 1 A); s_waitcnt vmcnt(6)
// keeps 2 tiles in flight at all times. Compute phase reads LDS only, so
// nothing else perturbs the vmcnt queue.
// LDS[row][slot16B] = global[row][slot ^ (row&7 or row&3)] (pre-swizzled
// source, rule #21), so ds_read_b128 spreads evenly over banks.
__global__ __launch_bounds__(256, 4) void k_gemm(const float* __restrict__ W,
                                                 const unsigned short* __restrict__ A,
                                                 float* __restrict__ Xp) {
    __shared__ char lds[NBUF * BUFB];
    const int nblk = blockIdx.x & 127;   // N tile (64 W-rows)
    const int kspl = blockIdx.x >> 7;    // K split
    const int w    = threadIdx.x >> 6;   // wave 0..3
    const int l    = threadIdx.x & 63;
    const int r    = l & 15;             // frag row-in-16
    const int g    = l >> 4;             // frag k-group

    const int  n0    = nblk * BN + w * 16;   // this wave's first W row
    const long kbase = (long)kspl * KCH;

    // staging geometry (per wave)
    const int wrow = l >> 3;             // W: row-in-8 per instr
    const int wslt = l & 7;              // W: 16B slot (8 per 128B row)
    const int arow = w * 16 + (l >> 2);  // A: shared rows, wave w covers 16
    const int aslt = l & 3;              // A: 16B slot (4 per 64B row)

    auto stage = [&](int tt, char* buf) {
        const long k0 = kbase + (long)tt * BK;   // element offset
        #pragma unroll
        for (int i = 0; i < 2; ++i) {    // W: 2 x 1KB, rows i*8..i*8+7 (local)
            int row  = i * 8 + wrow;
            int slot = wslt ^ (row & 7);
            gload16(W + (long)(n0 + row) * IN_DIMS + k0 + slot * 4,
                    buf + w * 2048 + i * 1024 + l * 16);
        }
        {                                 // A: 1 x 1KB, rows w*16..w*16+15
            int slot = aslt ^ (arow & 3);
            gload16(A + (long)arow * IN_DIMS + k0 + slot * 8,
                    buf + AOFF + w * 1024 + l * 16);
        }
    };

    stage(0, lds);                        // prologue: 2 tiles in flight
    stage(1, lds + BUFB);

    f32x4 acc0 = {0,0,0,0}, acc1 = {0,0,0,0}, acc2 = {0,0,0,0}, acc3 = {0,0,0,0};

    const int sa = g ^ (r & 3);           // A LDS slot for global k-slot g
    const int s0 = (g * 2) ^ (r & 7);     // W LDS slot for global k-slot g*2

    #pragma unroll 1
    for (int t = 0; t < NT; ++t) {
        int tsrc = (t + 2 < NT) ? (t + 2) : 0;        // dummy source on last 2
        int bidx = (t + 2) % NBUF;                    // dest never collides
        stage(tsrc, lds + bidx * BUFB);
        asm volatile("s_waitcnt vmcnt(6)" ::: "memory");  // own tile-t DMAs done
        __builtin_amdgcn_s_barrier();                 // all waves' tile-t visible

        const char* base = lds + (t % NBUF) * BUFB;
        const float* ldsW = (const float*)(base + w * 2048);
        const unsigned short* ldsA = (const unsigned short*)(base + AOFF);

        float4 w0 = *(const float4*)(ldsW + r * 32 + s0 * 4);
        float4 w1 = *(const float4*)(ldsW + r * 32 + (s0 ^ 1) * 4);
        s16x8 bw = cvt8(w0, w1);          // W[n0+r][k = g*8 .. g*8+7]
        s16x8 a0 = *(const s16x8*)(ldsA + ( 0 + r) * 32 + sa * 8);
        s16x8 a1 = *(const s16x8*)(ldsA + (16 + r) * 32 + sa * 8);
        s16x8 a2 = *(const s16x8*)(ldsA + (32 + r) * 32 + sa * 8);
        s16x8 a3 = *(const s16x8*)(ldsA + (48 + r) * 32 + sa * 8);
        acc0 = __builtin_amdgcn_mfma_f32_16x16x32_bf16(a0, bw, acc0, 0, 0, 0);
        acc1 = __builtin_amdgcn_mfma_f32_16x16x32_bf16(a1, bw, acc1, 0, 0, 0);
        acc2 = __builtin_amdgcn_mfma_f32_16x16x32_bf16(a2, bw, acc2, 0, 0, 0);
        acc3 = __builtin_amdgcn_mfma_f32_16x16x32_bf16(a3, bw, acc3, 0, 0, 0);

        __builtin_amdgcn_s_barrier();     // all reads of buf[t%3] done before reuse
    }

    // D layout: lane holds D[m = tb*16 + g*4 + q][n = n0 + r]
    float* xo = Xp + (long)kspl * BN * OUT_DIMS + n0 + r;
    #pragma unroll
    for (int q = 0; q < 4; ++q) {
        int m = g * 4 + q;
        xo[(long)(m     ) * OUT_DIMS] = acc0[q];
        xo[(long)(m + 16) * OUT_DIMS] = acc1[q];
        xo[(long)(m + 32) * OUT_DIMS] = acc2[q];
        xo[(long)(m + 48) * OUT_DIMS] = acc3[q];
    }
}

// ---- kernel 3: out(63x8192) = S(63x63) @ relu(sum_k Xp + b).view(8192,63)^T ----
__global__ __launch_bounds__(256) void k_out(const float* __restrict__ Xp,
                                             const float* __restrict__ S,
                                             const float* __restrict__ b,
                                             float* __restrict__ out) {
    __shared__ float sS[NLAB * NLAB];
    __shared__ float sml[32 * NLAB];
    const int k0 = blockIdx.x * 32;

    for (int p = threadIdx.x; p < NLAB * NLAB; p += 256) sS[p] = S[p];
    for (int p = threadIdx.x; p < 32 * NLAB; p += 256) {
        int gi = k0 * NLAB + p;          // flat index into X (row-major 63x8192)
        float v = 0.f;
        #pragma unroll
        for (int s = 0; s < KS; ++s)     // reduce split-K partials
            v += Xp[(long)s * 64 * OUT_DIMS + gi];
        v += b[gi & (OUT_DIMS - 1)];
        sml[p] = v > 0.f ? v : 0.f;
    }
    __syncthreads();

    for (int p = threadIdx.x; p < NLAB * 32; p += 256) {
        int i  = p >> 5;                 // output row
        int kk = p & 31;                 // output col within tile
        const float* srow = &sS[i * NLAB];
        const float* mrow = &sml[kk * NLAB];
        float sum = 0.f;
        #pragma unroll
        for (int j = 0; j < NLAB; ++j) sum += srow[j] * mrow[j];
        out[(long)i * OUT_DIMS + k0 + kk] = sum;
    }
}

extern "C" void kernel_launch(void* const* d_in, const int* in_sizes, int n_in,
                              void* d_out, int out_size, void* d_ws, size_t ws_size,
                              hipStream_t stream) {
    const float* Label = (const float*)d_in[0];   // 63x8192
    const float* S     = (const float*)d_in[1];   // 63x63
    const float* W     = (const float*)d_in[2];   // 8192x8192
    const float* b     = (const float*)d_in[3];   // 8192
    float* out = (float*)d_out;

    unsigned short* A  = (unsigned short*)d_ws;                      // 1 MB bf16 A
    float*          Xp = (float*)((char*)d_ws + 64 * IN_DIMS * 2);   // KS x 2 MB partials

    k_prep<<<dim3((64 * IN_DIMS / 4 + 255) / 256), dim3(256), 0, stream>>>(Label, A);
    k_gemm<<<dim3(128 * KS), dim3(256), 0, stream>>>(W, A, Xp);
    k_out <<<dim3(OUT_DIMS / 32), dim3(256), 0, stream>>>(Xp, S, b, out);
}